// Round 13
// baseline (225.226 us; speedup 1.0000x reference)
//
#include <hip/hip_runtime.h>

#define TPB 256
#define CHA 8192    // edges per k_binA block (512 threads)

typedef _Float16 half_t;
typedef _Float16 half4 __attribute__((ext_vector_type(4)));   // 8 B
typedef _Float16 half8 __attribute__((ext_vector_type(8)));   // 16 B
typedef float f32x4 __attribute__((ext_vector_type(4)));      // 16 B

// ---------------- pass A: bin edges into fixed-capacity buckets -------------
// bucket = dst >> 8, region [b*CAP, (b+1)*CAP); key = (src<<8)|(dst&255).
// Per-(block,bucket) contiguous runs reserved via one atomic; edges written
// DIRECTLY to their run slot (runs ~64B -> line-dense, no LDS staging).
// Blocks >= gBinA instead do the W->fp16 fragment reorder (prepW fused).
__global__ __launch_bounds__(512) void k_binA(unsigned* __restrict__ keys,
                                              int* __restrict__ bcursor,
                                              const int* __restrict__ ei,
                                              long long E, int NB, int CAP,
                                              int gBinA,
                                              half_t* __restrict__ Wf1,
                                              const float* __restrict__ W1,
                                              half_t* __restrict__ Wf2,
                                              const float* __restrict__ W2) {
  const int tid = threadIdx.x;

  if (blockIdx.x >= gBinA) {
    // ---- fused prepW: Wf[((kc*8+nt)*64+lane)*8 + j] = W[k][n] as fp16,
    // n = nt*16 + (lane&15), k = kc*32 + (lane>>4)*8 + j  (B-operand layout)
    int gid = (blockIdx.x - gBinA) * 512 + tid;   // 0..8191
    int f = gid & 4095;
    const float* W = (gid < 4096) ? W1 : W2;
    half_t* Wf = (gid < 4096) ? Wf1 : Wf2;
    int j0 = (f & 1) * 4;
    int lane = (f >> 1) & 63;
    int nt = (f >> 7) & 7;
    int kc = f >> 10;
    int n = nt * 16 + (lane & 15);
    int kb = kc * 32 + ((lane >> 4) << 3) + j0;
    half4 o;
    o.x = (_Float16)W[(kb + 0) * 128 + n];
    o.y = (_Float16)W[(kb + 1) * 128 + n];
    o.z = (_Float16)W[(kb + 2) * 128 + n];
    o.w = (_Float16)W[(kb + 3) * 128 + n];
    *(half4*)&Wf[f * 4] = o;
    return;
  }

  __shared__ int hist[512];
  __shared__ int base_run[512];
  __shared__ int bump[512];

  const long long e0 = (long long)blockIdx.x * CHA;
  const int cnt_here = (int)min((long long)CHA, E - e0);

  hist[tid] = 0; bump[tid] = 0;
  __syncthreads();

  for (int i = tid; i < cnt_here; i += 512)
    atomicAdd(&hist[ei[E + e0 + i] >> 8], 1);
  __syncthreads();

  // reserve per-bucket runs directly on the global cursors
  if (tid < NB) {
    int c = hist[tid];
    base_run[tid] = c ? atomicAdd(&bcursor[tid], c) : 0;
  }
  __syncthreads();

  // direct scatter: slot = b*CAP + base_run[b] + rank_within_block
  for (int i = tid; i < cnt_here; i += 512) {
    int s = ei[e0 + i];
    int d = ei[E + e0 + i];
    int b = d >> 8;
    int r = base_run[b] + atomicAdd(&bump[b], 1);
    if (r < CAP)
      keys[(long long)b * CAP + r] = ((unsigned)s << 8) | (unsigned)(d & 255);
  }
}

// ---------------- pass B: per-bucket counting sort + CSR emit ---------------
// block b owns nodes [b*256, b*256+256) and region [b*CAP, b*CAP+bcursor[b]).
__global__ __launch_bounds__(TPB) void k_binB(int* __restrict__ pay,
                                              int* __restrict__ cnt,
                                              int* __restrict__ off,
                                              float* __restrict__ dinv,
                                              const unsigned* __restrict__ keys,
                                              const int* __restrict__ bcursor,
                                              int N, int CAP) {
  __shared__ int lcnt[256], lofs[256], lcur[256];
  const int tid = threadIdx.x;
  const int b = blockIdx.x;
  const long long lo = (long long)b * CAP;
  const int total = min(bcursor[b], CAP);

  lcnt[tid] = 0; lcur[tid] = 0;
  __syncthreads();
  for (int i = tid; i < total; i += TPB)
    atomicAdd(&lcnt[__builtin_nontemporal_load(&keys[lo + i]) & 255], 1);
  __syncthreads();

  int v = lcnt[tid];
  lofs[tid] = v;
  __syncthreads();
  for (int ofs = 1; ofs < 256; ofs <<= 1) {
    int t = (tid >= ofs) ? lofs[tid - ofs] : 0;
    __syncthreads();
    lofs[tid] += t;
    __syncthreads();
  }
  lofs[tid] -= v;   // exclusive
  __syncthreads();

  const int node = (b << 8) + tid;
  if (node < N) {
    cnt[node] = v;
    off[node] = (int)lo + lofs[tid];
    dinv[node] = rsqrtf(1.0f + (float)v);
  }

  // place srcs; random 4B writes confined to this block's region
  for (int i = tid; i < total; i += TPB) {
    unsigned k = keys[lo + i];
    int l = (int)(k & 255u);
    int r = atomicAdd(&lcur[l], 1);
    pay[lo + lofs[l] + r] = (int)(k >> 8);
  }
}

// ---------- MFMA GEMM: hs[N,128](fp16) = dinv * (A[N,128] @ W[128,128]) -----
// 128-row tile, 256 threads (4 waves), wave rg owns rows rg*32..+31 (2 tiles).
// mfma_f32_16x16x32_f16: A m=lane&15,k=(lane>>4)*8+j; B n=lane&15,same k;
// C col=lane&15, row=(lane>>4)*4+reg  [m89-verified family].
template <int AF16>
__global__ __launch_bounds__(TPB) void k_gemm_mfma(const void* __restrict__ Ain,
                                                   const half_t* __restrict__ Wf,
                                                   const float* __restrict__ dinv,
                                                   half_t* __restrict__ hs, int N) {
  __shared__ half_t As[128 * 128];  // 32 KB, slot s=(mtile*4+kc)*64+lane
  __shared__ half_t Ws[16384];      // 32 KB, slot (kc*8+nt)*64+lane
  const int tid = threadIdx.x;
  const long long row0 = (long long)blockIdx.x * 128;

  { // stage Ws: flat coalesced copy
    half8* d = (half8*)Ws;
    const half8* s = (const half8*)Wf;
#pragma unroll
    for (int i = 0; i < 8; ++i) d[i * 256 + tid] = s[i * 256 + tid];
  }
  { // stage A fragment-ordered (slot-linear LDS writes: conflict-free)
#pragma unroll
    for (int i = 0; i < 8; ++i) {
      int s = i * 256 + tid;          // 0..2047
      int lane6 = s & 63;
      int grp = s >> 6;               // mtile*4 + kc, mtile 0..7
      int mtile = grp >> 2, kc = grp & 3;
      int m = lane6 & 15, kg = lane6 >> 4;
      long long gr = row0 + mtile * 16 + m;
      half8 hv = {};
      if (gr < (long long)N) {
        if (AF16) {
          hv = ((const half8*)Ain)[gr * 16 + kc * 4 + kg];
        } else {
          const f32x4* A4 = (const f32x4*)Ain;
          f32x4 v0 = __builtin_nontemporal_load(&A4[gr * 32 + kc * 8 + kg * 2]);
          f32x4 v1 =
              __builtin_nontemporal_load(&A4[gr * 32 + kc * 8 + kg * 2 + 1]);
          hv[0] = (_Float16)v0[0]; hv[1] = (_Float16)v0[1];
          hv[2] = (_Float16)v0[2]; hv[3] = (_Float16)v0[3];
          hv[4] = (_Float16)v1[0]; hv[5] = (_Float16)v1[1];
          hv[6] = (_Float16)v1[2]; hv[7] = (_Float16)v1[3];
        }
      }
      ((half8*)As)[s] = hv;
    }
  }
  __syncthreads();

  const int rg = tid >> 6, lane = tid & 63;
  f32x4 acc0[8], acc1[8];
#pragma unroll
  for (int nt = 0; nt < 8; ++nt) {
    f32x4 z = {0.f, 0.f, 0.f, 0.f};
    acc0[nt] = z; acc1[nt] = z;
  }
#pragma unroll
  for (int kc = 0; kc < 4; ++kc) {
    half8 a0 = ((const half8*)As)[((rg * 2 + 0) * 4 + kc) * 64 + lane];
    half8 a1 = ((const half8*)As)[((rg * 2 + 1) * 4 + kc) * 64 + lane];
#pragma unroll
    for (int nt = 0; nt < 8; ++nt) {
      half8 b = ((const half8*)Ws)[(kc * 8 + nt) * 64 + lane];
      acc0[nt] = __builtin_amdgcn_mfma_f32_16x16x32_f16(a0, b, acc0[nt], 0, 0, 0);
      acc1[nt] = __builtin_amdgcn_mfma_f32_16x16x32_f16(a1, b, acc1[nt], 0, 0, 0);
    }
  }

  // epilogue: scale by dinv, cvt fp16, store dense rows
  const int ncol = lane & 15;
  const int mbase = (lane >> 4) << 2;
#pragma unroll
  for (int mt = 0; mt < 2; ++mt) {
#pragma unroll
    for (int r = 0; r < 4; ++r) {
      long long grow = row0 + (rg * 2 + mt) * 16 + mbase + r;
      if (grow < (long long)N) {
        float sc = dinv[grow];
        half_t* dst = &hs[grow * 128 + ncol];
#pragma unroll
        for (int nt = 0; nt < 8; ++nt)
          dst[nt * 16] =
              (_Float16)(((mt == 0) ? acc0[nt][r] : acc1[nt][r]) * sc);
      }
    }
  }
}

// ---------------- gather-reduce aggregation (no atomics) --------------------
// out[i,:] = relu( b + dinv[i] * ( hs[i,:] + sum_{e: dst=i} hs[src,:] ) )
// 32-lane group per node; hs rows fp16 (256B), half4 per lane; f32 accum.
// pay loads + output stores are NONTEMPORAL to keep hs resident in L2.
template <int OUTF16>
__global__ __launch_bounds__(TPB) void k_agg(void* __restrict__ outp,
                                             const half4* __restrict__ hs,
                                             const int* __restrict__ pay,
                                             const int* __restrict__ off,
                                             const int* __restrict__ cnt,
                                             const float* __restrict__ dinv,
                                             const float* __restrict__ b, int N) {
  long long t = (long long)blockIdx.x * TPB + threadIdx.x;
  int g = (int)(t >> 5);
  if (g >= N) return;
  int c = (int)(t & 31);
  float di = dinv[g];
  f32x4 bv = *(const f32x4*)&b[c * 4];

  half4 hv = hs[(long long)g * 32 + c];   // self-loop term (prescaled)
  f32x4 acc;
  acc[0] = (float)hv.x; acc[1] = (float)hv.y;
  acc[2] = (float)hv.z; acc[3] = (float)hv.w;

  int p = off[g];
  const int en = p + cnt[g];

  for (; p + 8 <= en; p += 8) {
    int s[8];
#pragma unroll
    for (int u = 0; u < 8; ++u) s[u] = __builtin_nontemporal_load(&pay[p + u]);
    half4 v[8];
#pragma unroll
    for (int u = 0; u < 8; ++u) v[u] = hs[(long long)s[u] * 32 + c];
#pragma unroll
    for (int u = 0; u < 8; ++u) {
      acc[0] += (float)v[u].x; acc[1] += (float)v[u].y;
      acc[2] += (float)v[u].z; acc[3] += (float)v[u].w;
    }
  }
  if (p + 4 <= en) {
    int s[4];
#pragma unroll
    for (int u = 0; u < 4; ++u) s[u] = __builtin_nontemporal_load(&pay[p + u]);
    half4 v[4];
#pragma unroll
    for (int u = 0; u < 4; ++u) v[u] = hs[(long long)s[u] * 32 + c];
#pragma unroll
    for (int u = 0; u < 4; ++u) {
      acc[0] += (float)v[u].x; acc[1] += (float)v[u].y;
      acc[2] += (float)v[u].z; acc[3] += (float)v[u].w;
    }
    p += 4;
  }
  for (; p < en; ++p) {
    half4 v = hs[(long long)__builtin_nontemporal_load(&pay[p]) * 32 + c];
    acc[0] += (float)v.x; acc[1] += (float)v.y;
    acc[2] += (float)v.z; acc[3] += (float)v.w;
  }

  f32x4 o;
  o[0] = fmaxf(fmaf(acc[0], di, bv[0]), 0.f);
  o[1] = fmaxf(fmaf(acc[1], di, bv[1]), 0.f);
  o[2] = fmaxf(fmaf(acc[2], di, bv[2]), 0.f);
  o[3] = fmaxf(fmaf(acc[3], di, bv[3]), 0.f);

  if (OUTF16) {
    half4 ho;
    ho.x = (_Float16)o[0]; ho.y = (_Float16)o[1];
    ho.z = (_Float16)o[2]; ho.w = (_Float16)o[3];
    __builtin_nontemporal_store(ho, &((half4*)outp)[(long long)g * 32 + c]);
  } else {
    __builtin_nontemporal_store(o, &((f32x4*)outp)[(long long)g * 32 + c]);
  }
}

// ---------------------------------------------------------------------------

extern "C" void kernel_launch(void* const* d_in, const int* in_sizes, int n_in,
                              void* d_out, int out_size, void* d_ws, size_t ws_size,
                              hipStream_t stream) {
  const float* x  = (const float*)d_in[0];
  const float* W1 = (const float*)d_in[1];
  const float* b1 = (const float*)d_in[2];
  const float* W2 = (const float*)d_in[3];
  const float* b2 = (const float*)d_in[4];
  const int*   ei = (const int*)d_in[5];   // [2,E] int32

  const int N = in_sizes[0] / 128;
  const long long E = in_sizes[5] / 2;
  const int NB = (N + 255) >> 8;           // buckets of 256 nodes (<= 512)

  // fixed bucket capacity: 2x mean count, rounded up to 256 (>=4096)
  int CAP = (int)(((2 * (E / NB) + 255) / 256) * 256);
  if (CAP < 4096) CAP = 4096;

  // ws layout (16B alignment preserved)
  char* w = (char*)d_ws;
  half_t*   hs      = (half_t*)w;          w += (size_t)N * 128 * 2;
  half_t*   a1h     = (half_t*)w;          w += (size_t)N * 128 * 2;
  int*      pay     = (int*)w;             w += (size_t)NB * CAP * 4;
  unsigned* keys    = (unsigned*)w;        w += (size_t)NB * CAP * 4;
  int*      cnt     = (int*)w;             w += (size_t)N * 4;
  int*      off     = (int*)w;             w += (size_t)N * 4;
  float*    dinv    = (float*)w;           w += (size_t)N * 4;
  half_t*   Wf1     = (half_t*)w;          w += 16384 * 2;
  half_t*   Wf2     = (half_t*)w;          w += 16384 * 2;
  int*      bcursor = (int*)w;

  float* out = (float*)d_out;

  const long long n32 = (long long)N * 32;
  const int gN32 = (int)((n32 + TPB - 1) / TPB);
  const int gGemm = (N + 127) / 128;
  const int gBinA = (int)((E + CHA - 1) / CHA);

  // ---- fixed-capacity binned sort by dst (+ fused prepW) + CSR/dinv emit ----
  (void)hipMemsetAsync(bcursor, 0, (size_t)NB * 4, stream);
  k_binA<<<gBinA + 16, 512, 0, stream>>>(keys, bcursor, ei, E, NB, CAP, gBinA,
                                         Wf1, W1, Wf2, W2);
  k_binB<<<NB, TPB, 0, stream>>>(pay, cnt, off, dinv, keys, bcursor, N, CAP);

  // ---- layer 1: hs = fp16(dinv*(x@W1)); a1h = fp16(relu(b1 + dinv*agg)) ----
  k_gemm_mfma<0><<<gGemm, TPB, 0, stream>>>(x, Wf1, dinv, hs, N);
  k_agg<1><<<gN32, TPB, 0, stream>>>(a1h, (const half4*)hs, pay, off,
                                     cnt, dinv, b1, N);

  // ---- layer 2: hs = fp16(dinv*(a1h@W2)); out = relu(b2 + dinv*agg) ----
  k_gemm_mfma<1><<<gGemm, TPB, 0, stream>>>(a1h, Wf2, dinv, hs, N);
  k_agg<0><<<gN32, TPB, 0, stream>>>(out, (const half4*)hs, pay, off,
                                     cnt, dinv, b2, N);
}

// Round 14
// 206.006 us; speedup vs baseline: 1.0933x; 1.0933x over previous
//
#include <hip/hip_runtime.h>

#define TPB 256
#define CHA 8192    // edges per k_binA block (512 threads)

typedef _Float16 half_t;
typedef _Float16 half4 __attribute__((ext_vector_type(4)));   // 8 B
typedef _Float16 half8 __attribute__((ext_vector_type(8)));   // 16 B
typedef float f32x4 __attribute__((ext_vector_type(4)));      // 16 B

// ---------------- pass A: bin edges into fixed-capacity buckets -------------
// bucket = dst >> 8, region [b*CAP, (b+1)*CAP); key = (src<<8)|(dst&255).
// Per-(block,bucket) contiguous runs reserved via one atomic; edges written
// DIRECTLY to their run slot (runs ~64B -> line-dense, no LDS staging).
// Blocks >= gBinA instead do the W->fp16 fragment reorder (prepW fused).
__global__ __launch_bounds__(512) void k_binA(unsigned* __restrict__ keys,
                                              int* __restrict__ bcursor,
                                              const int* __restrict__ ei,
                                              long long E, int NB, int CAP,
                                              int gBinA,
                                              half_t* __restrict__ Wf1,
                                              const float* __restrict__ W1,
                                              half_t* __restrict__ Wf2,
                                              const float* __restrict__ W2) {
  const int tid = threadIdx.x;

  if (blockIdx.x >= gBinA) {
    // ---- fused prepW: Wf[((kc*8+nt)*64+lane)*8 + j] = W[k][n] as fp16,
    // n = nt*16 + (lane&15), k = kc*32 + (lane>>4)*8 + j  (B-operand layout)
    int gid = (blockIdx.x - gBinA) * 512 + tid;   // 0..8191
    int f = gid & 4095;
    const float* W = (gid < 4096) ? W1 : W2;
    half_t* Wf = (gid < 4096) ? Wf1 : Wf2;
    int j0 = (f & 1) * 4;
    int lane = (f >> 1) & 63;
    int nt = (f >> 7) & 7;
    int kc = f >> 10;
    int n = nt * 16 + (lane & 15);
    int kb = kc * 32 + ((lane >> 4) << 3) + j0;
    half4 o;
    o.x = (_Float16)W[(kb + 0) * 128 + n];
    o.y = (_Float16)W[(kb + 1) * 128 + n];
    o.z = (_Float16)W[(kb + 2) * 128 + n];
    o.w = (_Float16)W[(kb + 3) * 128 + n];
    *(half4*)&Wf[f * 4] = o;
    return;
  }

  __shared__ int hist[512];
  __shared__ int base_run[512];
  __shared__ int bump[512];

  const long long e0 = (long long)blockIdx.x * CHA;
  const int cnt_here = (int)min((long long)CHA, E - e0);

  hist[tid] = 0; bump[tid] = 0;
  __syncthreads();

  for (int i = tid; i < cnt_here; i += 512)
    atomicAdd(&hist[ei[E + e0 + i] >> 8], 1);
  __syncthreads();

  // reserve per-bucket runs directly on the global cursors
  if (tid < NB) {
    int c = hist[tid];
    base_run[tid] = c ? atomicAdd(&bcursor[tid], c) : 0;
  }
  __syncthreads();

  // direct scatter: slot = b*CAP + base_run[b] + rank_within_block
  for (int i = tid; i < cnt_here; i += 512) {
    int s = ei[e0 + i];
    int d = ei[E + e0 + i];
    int b = d >> 8;
    int r = base_run[b] + atomicAdd(&bump[b], 1);
    if (r < CAP)
      keys[(long long)b * CAP + r] = ((unsigned)s << 8) | (unsigned)(d & 255);
  }
}

// ---------------- pass B: per-bucket counting sort + CSR emit ---------------
// block b owns nodes [b*256, b*256+256) and region [b*CAP, b*CAP+bcursor[b]).
__global__ __launch_bounds__(TPB) void k_binB(int* __restrict__ pay,
                                              int* __restrict__ cnt,
                                              int* __restrict__ off,
                                              float* __restrict__ dinv,
                                              const unsigned* __restrict__ keys,
                                              const int* __restrict__ bcursor,
                                              int N, int CAP) {
  __shared__ int lcnt[256], lofs[256], lcur[256];
  const int tid = threadIdx.x;
  const int b = blockIdx.x;
  const long long lo = (long long)b * CAP;
  const int total = min(bcursor[b], CAP);

  lcnt[tid] = 0; lcur[tid] = 0;
  __syncthreads();
  for (int i = tid; i < total; i += TPB)
    atomicAdd(&lcnt[keys[lo + i] & 255], 1);
  __syncthreads();

  int v = lcnt[tid];
  lofs[tid] = v;
  __syncthreads();
  for (int ofs = 1; ofs < 256; ofs <<= 1) {
    int t = (tid >= ofs) ? lofs[tid - ofs] : 0;
    __syncthreads();
    lofs[tid] += t;
    __syncthreads();
  }
  lofs[tid] -= v;   // exclusive
  __syncthreads();

  const int node = (b << 8) + tid;
  if (node < N) {
    cnt[node] = v;
    off[node] = (int)lo + lofs[tid];
    dinv[node] = rsqrtf(1.0f + (float)v);
  }

  // place srcs; random 4B writes confined to this block's region
  for (int i = tid; i < total; i += TPB) {
    unsigned k = keys[lo + i];
    int l = (int)(k & 255u);
    int r = atomicAdd(&lcur[l], 1);
    pay[lo + lofs[l] + r] = (int)(k >> 8);
  }
}

// ---------- MFMA GEMM: hs[N,128](fp16) = dinv * (A[N,128] @ W[128,128]) -----
// 128-row tile, 256 threads (4 waves), wave rg owns rows rg*32..+31 (2 tiles).
// mfma_f32_16x16x32_f16: A m=lane&15,k=(lane>>4)*8+j; B n=lane&15,same k;
// C col=lane&15, row=(lane>>4)*4+reg  [m89-verified family].
template <int AF16>
__global__ __launch_bounds__(TPB) void k_gemm_mfma(const void* __restrict__ Ain,
                                                   const half_t* __restrict__ Wf,
                                                   const float* __restrict__ dinv,
                                                   half_t* __restrict__ hs, int N) {
  __shared__ half_t As[128 * 128];  // 32 KB, slot s=(mtile*4+kc)*64+lane
  __shared__ half_t Ws[16384];      // 32 KB, slot (kc*8+nt)*64+lane
  const int tid = threadIdx.x;
  const long long row0 = (long long)blockIdx.x * 128;

  { // stage Ws: flat coalesced copy
    half8* d = (half8*)Ws;
    const half8* s = (const half8*)Wf;
#pragma unroll
    for (int i = 0; i < 8; ++i) d[i * 256 + tid] = s[i * 256 + tid];
  }
  { // stage A fragment-ordered (slot-linear LDS writes: conflict-free)
#pragma unroll
    for (int i = 0; i < 8; ++i) {
      int s = i * 256 + tid;          // 0..2047
      int lane6 = s & 63;
      int grp = s >> 6;               // mtile*4 + kc, mtile 0..7
      int mtile = grp >> 2, kc = grp & 3;
      int m = lane6 & 15, kg = lane6 >> 4;
      long long gr = row0 + mtile * 16 + m;
      half8 hv = {};
      if (gr < (long long)N) {
        if (AF16) {
          hv = ((const half8*)Ain)[gr * 16 + kc * 4 + kg];
        } else {
          const f32x4* A4 = (const f32x4*)Ain;
          f32x4 v0 = A4[gr * 32 + kc * 8 + kg * 2];
          f32x4 v1 = A4[gr * 32 + kc * 8 + kg * 2 + 1];
          hv[0] = (_Float16)v0[0]; hv[1] = (_Float16)v0[1];
          hv[2] = (_Float16)v0[2]; hv[3] = (_Float16)v0[3];
          hv[4] = (_Float16)v1[0]; hv[5] = (_Float16)v1[1];
          hv[6] = (_Float16)v1[2]; hv[7] = (_Float16)v1[3];
        }
      }
      ((half8*)As)[s] = hv;
    }
  }
  __syncthreads();

  const int rg = tid >> 6, lane = tid & 63;
  f32x4 acc0[8], acc1[8];
#pragma unroll
  for (int nt = 0; nt < 8; ++nt) {
    f32x4 z = {0.f, 0.f, 0.f, 0.f};
    acc0[nt] = z; acc1[nt] = z;
  }
#pragma unroll
  for (int kc = 0; kc < 4; ++kc) {
    half8 a0 = ((const half8*)As)[((rg * 2 + 0) * 4 + kc) * 64 + lane];
    half8 a1 = ((const half8*)As)[((rg * 2 + 1) * 4 + kc) * 64 + lane];
#pragma unroll
    for (int nt = 0; nt < 8; ++nt) {
      half8 b = ((const half8*)Ws)[(kc * 8 + nt) * 64 + lane];
      acc0[nt] = __builtin_amdgcn_mfma_f32_16x16x32_f16(a0, b, acc0[nt], 0, 0, 0);
      acc1[nt] = __builtin_amdgcn_mfma_f32_16x16x32_f16(a1, b, acc1[nt], 0, 0, 0);
    }
  }

  // epilogue: scale by dinv, cvt fp16, store dense rows
  const int ncol = lane & 15;
  const int mbase = (lane >> 4) << 2;
#pragma unroll
  for (int mt = 0; mt < 2; ++mt) {
#pragma unroll
    for (int r = 0; r < 4; ++r) {
      long long grow = row0 + (rg * 2 + mt) * 16 + mbase + r;
      if (grow < (long long)N) {
        float sc = dinv[grow];
        half_t* dst = &hs[grow * 128 + ncol];
#pragma unroll
        for (int nt = 0; nt < 8; ++nt)
          dst[nt * 16] =
              (_Float16)(((mt == 0) ? acc0[nt][r] : acc1[nt][r]) * sc);
      }
    }
  }
}

// ---------------- gather-reduce aggregation (no atomics) --------------------
// out[i,:] = relu( b + dinv[i] * ( hs[i,:] + sum_{e: dst=i} hs[src,:] ) )
// 32-lane group per node; hs rows fp16 (256B), half4 per lane; f32 accum.
template <int OUTF16>
__global__ __launch_bounds__(TPB) void k_agg(void* __restrict__ outp,
                                             const half4* __restrict__ hs,
                                             const int* __restrict__ pay,
                                             const int* __restrict__ off,
                                             const int* __restrict__ cnt,
                                             const float* __restrict__ dinv,
                                             const float* __restrict__ b, int N) {
  long long t = (long long)blockIdx.x * TPB + threadIdx.x;
  int g = (int)(t >> 5);
  if (g >= N) return;
  int c = (int)(t & 31);
  float di = dinv[g];
  f32x4 bv = *(const f32x4*)&b[c * 4];

  half4 hv = hs[(long long)g * 32 + c];   // self-loop term (prescaled)
  f32x4 acc;
  acc[0] = (float)hv.x; acc[1] = (float)hv.y;
  acc[2] = (float)hv.z; acc[3] = (float)hv.w;

  int p = off[g];
  const int en = p + cnt[g];

  for (; p + 8 <= en; p += 8) {
    int s[8];
#pragma unroll
    for (int u = 0; u < 8; ++u) s[u] = pay[p + u];
    half4 v[8];
#pragma unroll
    for (int u = 0; u < 8; ++u) v[u] = hs[(long long)s[u] * 32 + c];
#pragma unroll
    for (int u = 0; u < 8; ++u) {
      acc[0] += (float)v[u].x; acc[1] += (float)v[u].y;
      acc[2] += (float)v[u].z; acc[3] += (float)v[u].w;
    }
  }
  if (p + 4 <= en) {
    int s[4];
#pragma unroll
    for (int u = 0; u < 4; ++u) s[u] = pay[p + u];
    half4 v[4];
#pragma unroll
    for (int u = 0; u < 4; ++u) v[u] = hs[(long long)s[u] * 32 + c];
#pragma unroll
    for (int u = 0; u < 4; ++u) {
      acc[0] += (float)v[u].x; acc[1] += (float)v[u].y;
      acc[2] += (float)v[u].z; acc[3] += (float)v[u].w;
    }
    p += 4;
  }
  for (; p < en; ++p) {
    half4 v = hs[(long long)pay[p] * 32 + c];
    acc[0] += (float)v.x; acc[1] += (float)v.y;
    acc[2] += (float)v.z; acc[3] += (float)v.w;
  }

  f32x4 o;
  o[0] = fmaxf(fmaf(acc[0], di, bv[0]), 0.f);
  o[1] = fmaxf(fmaf(acc[1], di, bv[1]), 0.f);
  o[2] = fmaxf(fmaf(acc[2], di, bv[2]), 0.f);
  o[3] = fmaxf(fmaf(acc[3], di, bv[3]), 0.f);

  if (OUTF16) {
    half4 ho;
    ho.x = (_Float16)o[0]; ho.y = (_Float16)o[1];
    ho.z = (_Float16)o[2]; ho.w = (_Float16)o[3];
    ((half4*)outp)[(long long)g * 32 + c] = ho;
  } else {
    ((f32x4*)outp)[(long long)g * 32 + c] = o;
  }
}

// ---------------------------------------------------------------------------

extern "C" void kernel_launch(void* const* d_in, const int* in_sizes, int n_in,
                              void* d_out, int out_size, void* d_ws, size_t ws_size,
                              hipStream_t stream) {
  const float* x  = (const float*)d_in[0];
  const float* W1 = (const float*)d_in[1];
  const float* b1 = (const float*)d_in[2];
  const float* W2 = (const float*)d_in[3];
  const float* b2 = (const float*)d_in[4];
  const int*   ei = (const int*)d_in[5];   // [2,E] int32

  const int N = in_sizes[0] / 128;
  const long long E = in_sizes[5] / 2;
  const int NB = (N + 255) >> 8;           // buckets of 256 nodes (<= 512)

  // fixed bucket capacity: 2x mean count, rounded up to 256 (>=4096)
  int CAP = (int)(((2 * (E / NB) + 255) / 256) * 256);
  if (CAP < 4096) CAP = 4096;

  // ws layout (16B alignment preserved)
  char* w = (char*)d_ws;
  half_t*   hs      = (half_t*)w;          w += (size_t)N * 128 * 2;
  half_t*   a1h     = (half_t*)w;          w += (size_t)N * 128 * 2;
  int*      pay     = (int*)w;             w += (size_t)NB * CAP * 4;
  unsigned* keys    = (unsigned*)w;        w += (size_t)NB * CAP * 4;
  int*      cnt     = (int*)w;             w += (size_t)N * 4;
  int*      off     = (int*)w;             w += (size_t)N * 4;
  float*    dinv    = (float*)w;           w += (size_t)N * 4;
  half_t*   Wf1     = (half_t*)w;          w += 16384 * 2;
  half_t*   Wf2     = (half_t*)w;          w += 16384 * 2;
  int*      bcursor = (int*)w;

  float* out = (float*)d_out;

  const long long n32 = (long long)N * 32;
  const int gN32 = (int)((n32 + TPB - 1) / TPB);
  const int gGemm = (N + 127) / 128;
  const int gBinA = (int)((E + CHA - 1) / CHA);

  // ---- fixed-capacity binned sort by dst (+ fused prepW) + CSR/dinv emit ----
  (void)hipMemsetAsync(bcursor, 0, (size_t)NB * 4, stream);
  k_binA<<<gBinA + 16, 512, 0, stream>>>(keys, bcursor, ei, E, NB, CAP, gBinA,
                                         Wf1, W1, Wf2, W2);
  k_binB<<<NB, TPB, 0, stream>>>(pay, cnt, off, dinv, keys, bcursor, N, CAP);

  // ---- layer 1: hs = fp16(dinv*(x@W1)); a1h = fp16(relu(b1 + dinv*agg)) ----
  k_gemm_mfma<0><<<gGemm, TPB, 0, stream>>>(x, Wf1, dinv, hs, N);
  k_agg<1><<<gN32, TPB, 0, stream>>>(a1h, (const half4*)hs, pay, off,
                                     cnt, dinv, b1, N);

  // ---- layer 2: hs = fp16(dinv*(a1h@W2)); out = relu(b2 + dinv*agg) ----
  k_gemm_mfma<1><<<gGemm, TPB, 0, stream>>>(a1h, Wf2, dinv, hs, N);
  k_agg<0><<<gN32, TPB, 0, stream>>>(out, (const half4*)hs, pay, off,
                                     cnt, dinv, b2, N);
}